// Round 14
// baseline (200.424 us; speedup 1.0000x reference)
//
#include <hip/hip_runtime.h>
#include <hip/hip_bf16.h>
#include <cmath>

#define DIM 512
#define HID 256
#define ROWS_PB 32       // rows per block (100000 = 3125 * 32, no tail)
#define NCHUNK 16        // K chunks of 32
#define CB 16384         // B chunk bytes: 32k * 256c * 2B

typedef __attribute__((ext_vector_type(8))) short short8;
typedef __attribute__((ext_vector_type(4))) float f32x4;
typedef __attribute__((ext_vector_type(16))) float f32x16;
typedef __attribute__((ext_vector_type(4))) unsigned int u32x4;

__device__ __forceinline__ unsigned short f2bf(float f) {
  union { float f; unsigned u; } v; v.f = f;
  unsigned u = v.u;
  return (unsigned short)((u + 0x7FFFu + ((u >> 16) & 1u)) >> 16);
}
__device__ __forceinline__ float bf2f(short h) {
  union { unsigned u; float f; } v;
  v.u = ((unsigned)(unsigned short)h) << 16;
  return v.f;
}

// Pre-swizzle W1 (fp32 [512,256] row-major) into bf16 fragment order:
// w1s[((k>>3)*HID + c)*8 + (k&7)]. This kg-octet layout serves BOTH the
// 16x16x32 and 32x32x16 fragment shapes. K-chunk c (32 k's) is the
// contiguous 16 KB at byte offset c*16384.
__global__ void w1_swz_kernel(const float* __restrict__ W1,
                              unsigned short* __restrict__ w1s) {
  int tid = blockIdx.x * blockDim.x + threadIdx.x;
  if (tid >= DIM * HID) return;
  int k = tid / HID;
  int c = tid - k * HID;
  w1s[(((k >> 3) * HID) + c) * 8 + (k & 7)] = f2bf(W1[tid]);
}

__device__ __forceinline__ short8 cvt8(const f32x4 p0, const f32x4 p1) {
  short8 r;
  r[0] = (short)f2bf(p0[0]); r[1] = (short)f2bf(p0[1]);
  r[2] = (short)f2bf(p0[2]); r[3] = (short)f2bf(p0[3]);
  r[4] = (short)f2bf(p1[0]); r[5] = (short)f2bf(p1[1]);
  r[6] = (short)f2bf(p1[2]); r[7] = (short)f2bf(p1[3]);
  return r;
}

__device__ __forceinline__ void wcombine(float wa, const short8 a, float wb,
                                         const short8 b, f32x4& o0, f32x4& o1) {
#pragma unroll
  for (int i = 0; i < 4; ++i) {
    o0[i] = wa * bf2f(a[i]) + wb * bf2f(b[i]);
    o1[i] = wa * bf2f(a[i + 4]) + wb * bf2f(b[i + 4]);
  }
}

// 4 waves / 32 rows. Wave w: src s=w&1, col-half h=w>>1 (32x32x16 MFMA:
// each wave computes ALL 32 rows of its source over 128 hidden cols).
// Phase 1: pure HBM burst -> Az (64 KB bf16 fragments; z read ONCE). R13's
//          proven staging, wave roles (s, tile=h).
// Phase 2: L2-only K-loop, single-buffered B via T14 reg-staging. Per chunk
//          per wave only 2 A + 8 B ds_reads + 8 MFMAs (32x32 halves the
//          LDS B-bytes per FLOP vs 16x16); natural interleave (no
//          sched_barrier) so the compiler's lgkmcnt pipelining engages.
// Phase 3: logits via 32-lane shuffle reduce + xs2 combine; epilogue
//          entirely from Az (no HBM reads).
__global__ __launch_bounds__(256, 2) void fa_main_kernel(
    const float* __restrict__ z1, const float* __restrict__ z2,
    const unsigned short* __restrict__ w1s,
    const float* __restrict__ bias1, const float* __restrict__ W2,
    const float* __restrict__ bias2, float* __restrict__ out, int n) {
  // Az [s][chunk][tile16][lane] short8 = 64 KB; Bs 16 KB (xs2 aliases Bs
  // after the K-loop). Total 80 KB -> 2 blocks/CU.
  __shared__ char smem[81920];
  short8* Az = (short8*)smem;
  char* Bs = smem + 65536;
  float* xs2 = (float*)(smem + 65536);  // [s][h][row32], post-K-loop only

  const int t = threadIdx.x;
  const int w = t >> 6;
  const int l = t & 63;
  const int l15 = l & 15, l16 = l >> 4;
  const int l31 = l & 31, lhi = l >> 5;
  const int s = w & 1;   // source
  const int h = w >> 1;  // col-half for compute; row-tile for staging
  const int row0 = blockIdx.x * ROWS_PB;
  const int myrow = row0 + h * 16 + l15;  // staging row
  const bool rok = myrow < n;
  const float* zz = s ? z2 : z1;
  const float* ap = zz + (size_t)myrow * DIM + (l16 << 3);
  const f32x4 zf4 = (f32x4){0.f, 0.f, 0.f, 0.f};

  // T14 B-staging: 16 KB/chunk = 4 x u32x4 per thread.
  u32x4 breg0, breg1, breg2, breg3;
#define BLOAD(c)                                            \
  {                                                         \
    const u32x4* g = (const u32x4*)w1s + (c) * 1024 + t;    \
    breg0 = g[0];                                           \
    breg1 = g[256];                                         \
    breg2 = g[512];                                         \
    breg3 = g[768];                                         \
  }
#define BWRITE()                                            \
  {                                                         \
    u32x4* d = (u32x4*)Bs + t;                              \
    d[0] = breg0;                                           \
    d[256] = breg1;                                         \
    d[512] = breg2;                                         \
    d[768] = breg3;                                         \
  }

  // ---- Phase 1: B[0] issue, then the A burst (4 groups x 8 indep loads).
  BLOAD(0);
  __builtin_amdgcn_sched_barrier(0);
#pragma unroll
  for (int g = 0; g < 4; ++g) {
    f32x4 p[4][2];
#pragma unroll
    for (int j = 0; j < 4; ++j) {
      const float* pp = ap + (((g << 2) + j) << 5);
      p[j][0] = rok ? *(const f32x4*)(pp) : zf4;
      p[j][1] = rok ? *(const f32x4*)(pp + 4) : zf4;
    }
#pragma unroll
    for (int j = 0; j < 4; ++j)
      Az[((s * NCHUNK + (g << 2) + j) * 2 + h) * 64 + l] =
          cvt8(p[j][0], p[j][1]);
  }
  BWRITE();  // waits only breg (L2, landed long ago)
  __syncthreads();  // Az + B[0] visible

  f32x16 acc[4];
#pragma unroll
  for (int g = 0; g < 4; ++g)
#pragma unroll
    for (int r = 0; r < 16; ++r) acc[g][r] = 0.f;

  // A-fragment remap (32x32 lane lf, chunk c, kslice ks):
  //   Az[((s*16+c)*2 + (lf&31)>>4)*64 + (lf&15) + ((ks*2 + (lf>>5))<<4)]
  const int aTl = (l31 >> 4);
  const int aLo = (l & 15);
  // B-fragment (chunk-resident Bs, kslice ks, group g):
  //   short8-idx ((ks*2 + lhi)*256) + (h*4+g)*32 + l31
  const int bBase = (h << 2) * 32 + l31;

  // ---- Phase 2: K-loop, L2-only. 2 A + 8 B reads + 8 MFMAs per chunk.
#pragma unroll
  for (int c = 0; c < NCHUNK; ++c) {
    if (c + 1 < NCHUNK) BLOAD(c + 1);  // early issue (L2)
    __builtin_amdgcn_sched_barrier(0);
    const short8* azc = Az + ((s * NCHUNK + c) * 2 + aTl) * 64 + aLo;
    const short8* bsc = (const short8*)Bs;
#pragma unroll
    for (int ks = 0; ks < 2; ++ks) {
      const short8 af = azc[((ks << 1) + lhi) << 4];
      const short8* bp = bsc + (((ks << 1) + lhi) << 8) + bBase;
#pragma unroll
      for (int g = 0; g < 4; ++g) {
        const short8 bf = bp[g << 5];
        acc[g] = __builtin_amdgcn_mfma_f32_32x32x16_bf16(af, bf, acc[g], 0, 0,
                                                         0);
      }
    }
    __syncthreads();  // all Bs reads done; breg landed
    if (c + 1 < NCHUNK) BWRITE();
    __syncthreads();  // new B chunk visible
  }

  // ---- Phase 3a: logits. C/D (32x32): col = (h*4+g)*32 + l31,
  // row = (r&3) + 8*(r>>2) + 4*lhi.
  float part[16];
#pragma unroll
  for (int r = 0; r < 16; ++r) part[r] = 0.f;
#pragma unroll
  for (int g = 0; g < 4; ++g) {
    const int cc = ((h << 2) + g) * 32 + l31;
    const float w2v = W2[cc];
    const float b1v = bias1[cc];
#pragma unroll
    for (int r = 0; r < 16; ++r) {
      const float hh = acc[g][r] + b1v;
      part[r] += (hh > 0.f) ? hh * w2v : 0.f;
    }
  }
#pragma unroll
  for (int r = 0; r < 16; ++r) {
#pragma unroll
    for (int m = 1; m < 32; m <<= 1) part[r] += __shfl_xor(part[r], m, 64);
  }
  if (l31 == 0) {
#pragma unroll
    for (int r = 0; r < 16; ++r) {
      const int row = (r & 3) + ((r >> 2) << 3) + (lhi << 2);
      xs2[(s * 2 + h) * 32 + row] = part[r];
    }
  }
  __syncthreads();

  // ---- Phase 3b: scores + output, entirely from Az (no HBM reads).
  // Wave w: rows tile tl2 = w&1, column chunks (w>>1)*8..+8 (R13 pattern).
  const int tl2 = w & 1;
  const int orow_l = tl2 * 16 + l15;
  const int grow = row0 + orow_l;
  const float x = xs2[0 * 32 + orow_l] + xs2[1 * 32 + orow_l];
  const float y = xs2[2 * 32 + orow_l] + xs2[3 * 32 + orow_l];
  const float sx = 1.f / (1.f + __expf(y - x));  // b2 cancels
  const float sy = 1.f - sx;
  float* orow = out + (size_t)grow * DIM + (l16 << 3);
  if (grow < n) {
#pragma unroll
    for (int j = 0; j < 8; ++j) {
      const int cc = ((w >> 1) << 3) + j;
      const short8 a0 = Az[((0 * NCHUNK + cc) * 2 + tl2) * 64 + l];
      const short8 a1 = Az[((1 * NCHUNK + cc) * 2 + tl2) * 64 + l];
      f32x4 o0, o1;
      wcombine(sx, a0, sy, a1, o0, o1);
      *(f32x4*)(orow + (cc << 5)) = o0;
      *(f32x4*)(orow + (cc << 5) + 4) = o1;
    }
  }
#undef BLOAD
#undef BWRITE
}

extern "C" void kernel_launch(void* const* d_in, const int* in_sizes, int n_in,
                              void* d_out, int out_size, void* d_ws,
                              size_t ws_size, hipStream_t stream) {
  const float* z1 = (const float*)d_in[0];
  const float* z2 = (const float*)d_in[1];
  const float* W1 = (const float*)d_in[2];
  const float* b1 = (const float*)d_in[3];
  const float* W2 = (const float*)d_in[4];
  const float* b2 = (const float*)d_in[5];
  float* out = (float*)d_out;
  const int n = in_sizes[0] / DIM;
  unsigned short* w1s = (unsigned short*)d_ws;  // 512*256*2 = 256 KB

  hipLaunchKernelGGL(w1_swz_kernel, dim3((DIM * HID + 255) / 256), dim3(256),
                     0, stream, W1, w1s);
  const int nwg = (n + ROWS_PB - 1) / ROWS_PB;
  hipLaunchKernelGGL(fa_main_kernel, dim3(nwg), dim3(256), 0, stream, z1, z2,
                     w1s, b1, W2, b2, out, n);
}